// Round 12
// baseline (79.896 us; speedup 1.0000x reference)
//
#include <hip/hip_runtime.h>
#include <hip/hip_bf16.h>

// ConvexWidthUpsampler R12: R11 structure + exact-fit LDS (32768 B -> 5 blocks/CU).
// z stays in registers (permuted-M2 trick):
//   Round 1: z[n,px] = mfma(B1, a0); zfrag = packed |z| is a legal B-operand
//   under channel perm pi(k) = (k&4?16:0)+(k>>3)*4+(k&3) (M2p pre-permuted).
//   Round 2: m = mfma(M2p, zfrag) + mfma(B2, a0) -- no z LDS roundtrip.
// a0 k16..31 zeros now come from an exec-masked read (lq<2) into zeroed regs.
// Persistent grid NBLK=1280 (5 blocks/CU exactly), x prefetch 1 tile ahead.
// B=16,C=1,H=512,W=512,up=(1,3). Output [16,1,512,1536] f32.

#define BB 16
#define HH 512
#define WW 512
#define HID 32
#define NM 27
#define LOG2E 1.44269504088896340736f
#define NT 16384
#define NBLK 1280   // 5 blocks/CU x 256 CUs; grid-stride covers NT tiles

typedef short bf16x8 __attribute__((ext_vector_type(8)));
typedef float f32x4  __attribute__((ext_vector_type(4)));
typedef unsigned int u32;
typedef u32 u32x4 __attribute__((ext_vector_type(4)));

__device__ __forceinline__ u32 pk2(float a, float b) {
    union { __hip_bfloat162 h2; u32 u; } cv;
    cv.h2 = __float22bfloat162_rn(make_float2(a, b));
    return cv.u;
}

// Compiler memory fence (free at runtime): blocks CSE/TBAA reordering of LDS
// ops across stages; a wave's DS instructions execute in issue order in HW.
__device__ __forceinline__ void lds_fence() {
    asm volatile("" ::: "memory");
    __builtin_amdgcn_sched_barrier(0);
}

// Clamped-address 3x3 load: addresses always in-bounds, zeros via cndmask.
__device__ __forceinline__ void load_xv(const float* __restrict__ x, int tile,
                                        int tid, float xv[9]) {
    const int p    = tile * 256 + tid;
    const int wcol = p & (WW - 1);
    const int t    = p >> 9;
    const int hrow = t & (HH - 1);
    const int bidx = t >> 9;
    const float* xb = x + (size_t)bidx * (HH * WW);
    int hy[3], wx[3];
    bool hok[3], wok[3];
#pragma unroll
    for (int i = 0; i < 3; ++i) {
        const int h = hrow + i - 1;
        hok[i] = (unsigned)h < (unsigned)HH;
        hy[i]  = h < 0 ? 0 : (h > HH - 1 ? HH - 1 : h);
        const int w = wcol + i - 1;
        wok[i] = (unsigned)w < (unsigned)WW;
        wx[i]  = w < 0 ? 0 : (w > WW - 1 ? WW - 1 : w);
    }
#pragma unroll
    for (int ki = 0; ki < 3; ++ki)
#pragma unroll
        for (int kj = 0; kj < 3; ++kj) {
            const float v = xb[hy[ki] * WW + wx[kj]];
            xv[ki * 3 + kj] = (hok[ki] && wok[kj]) ? v : 0.0f;
        }
}

// ws bf16 layout (hi-only, 3072 elems = 6 KB):
//   [0   ..1023] B2_32 [32 n][32 k]: k<9 M1[n][k], k==9 bias'[n], else 0 (xlog2e)
//   [1024..2047] M2p   [32 n][32 k]: M2[n][pi(k)] (xlog2e), n>=27 -> 0
//   [2048..3071] B1    [32 n][32 k]: k<9 w1[n][k], k==9 b1[n], else 0
__global__ void prep_B(const float* __restrict__ w1, const float* __restrict__ b1,
                       const float* __restrict__ alpha, const float* __restrict__ w2,
                       const float* __restrict__ b2, __hip_bfloat16* __restrict__ ws) {
    const int i = blockIdx.x * 256 + threadIdx.x;
    if (i >= 3072) return;
    const int sec = i >> 10;
    const int r   = i & 1023;
    const int n   = r >> 5, k = r & 31;
    float v = 0.0f;
    if (sec == 0) {
        if (n < NM) {
            if (k < 9) {
                for (int c = 0; c < HID; ++c)
                    v += w2[n * HID + c] * (0.5f * (1.0f + alpha[c])) * w1[c * 9 + k];
            } else if (k == 9) {
                v = b2[n];
                for (int c = 0; c < HID; ++c)
                    v += w2[n * HID + c] * (0.5f * (1.0f + alpha[c])) * b1[c];
            }
        }
        v *= LOG2E;
    } else if (sec == 1) {
        if (n < NM) {
            const int c = ((k & 4) ? 16 : 0) + (k >> 3) * 4 + (k & 3);  // pi(k)
            v = w2[n * HID + c] * (0.5f * (1.0f - alpha[c])) * LOG2E;
        }
    } else {
        v = (k < 9) ? w1[n * 9 + k] : (k == 9 ? b1[n] : 0.0f);
    }
    ws[i] = __float2bfloat16(v);
}

__global__ __launch_bounds__(256, 5) void convex_upsample_mfma8(
    const float* __restrict__ x,            // [16,1,512,512]
    const __hip_bfloat16* __restrict__ ws,  // prep output
    float* __restrict__ out)                // [16,1,512,1536]
{
    __shared__ char lds_raw[4][64 * 128];   // 32768 B exactly -> 5 blocks/CU

    const int tid  = threadIdx.x;
    const int wv   = tid >> 6;
    const int lane = tid & 63;
    const int l16  = lane & 15;
    const int lq   = lane >> 4;
    char* wbase = lds_raw[wv];
    const int sx  = (lane & 7) << 4;
    const int asx = (l16 & 7) << 4;

    // persistent weight fragments (hi only): lane row n = nt*16+l16, k = lq*8+i
    bf16x8 Bf2[2], M2p[2], Bf1[2];
#pragma unroll
    for (int nt = 0; nt < 2; ++nt) {
        const int ro = (nt * 16 + l16) * 32 + lq * 8;
        Bf2[nt] = *(const bf16x8*)(ws + ro);
        M2p[nt] = *(const bf16x8*)(ws + 1024 + ro);
        Bf1[nt] = *(const bf16x8*)(ws + 2048 + ro);
    }

    int tb = blockIdx.x;
    float xv[9];
    load_xv(x, tb, tid, xv);

    while (tb < NT) {
        const int tn  = tb + NBLK;
        const int tpf = (tn < NT) ? tn : 0;
        float xn[9];
        load_xv(x, tpf, tid, xn);   // prefetch next tile during this compute

        // ---- init my row bytes 0..31: k0..8=xv, k9=1, k10..15=0 ----
        char* myrow = wbase + lane * 128;
        *(u32x4*)(myrow + (0 ^ sx))  = (u32x4){pk2(xv[0], xv[1]), pk2(xv[2], xv[3]),
                                               pk2(xv[4], xv[5]), pk2(xv[6], xv[7])};
        *(u32x4*)(myrow + (16 ^ sx)) = (u32x4){pk2(xv[8], 1.0f), 0u, 0u, 0u};

        lds_fence();   // init writes -> cross-lane a0 reads

        // ---- hoisted a0 reads; lanes lq>=2 hold zeros (exec-masked read) ----
        bf16x8 a0[4];
#pragma unroll
        for (int mt = 0; mt < 4; ++mt) {
            a0[mt] = (bf16x8){0, 0, 0, 0, 0, 0, 0, 0};
            if (lq < 2) {
                const char* ab = wbase + (mt * 16 + l16) * 128;
                a0[mt] = *(const bf16x8*)(ab + ((lq * 16) ^ asx));
            }
        }

        lds_fence();   // a0 reads -> scatters below (TBAA/reorder guard)

        // ---- per mt: z in-register -> logits -> scatter ----
#pragma unroll
        for (int mt = 0; mt < 4; ++mt) {
            char* ab = wbase + (mt * 16 + l16) * 128;
            // round 1: z[ch][px]; lane(l16,lq) gets ch = {lq*4+r, 16+lq*4+r}, px = l16
            f32x4 z0 = {0.f, 0.f, 0.f, 0.f}, z1 = {0.f, 0.f, 0.f, 0.f};
            z0 = __builtin_amdgcn_mfma_f32_16x16x32_bf16(Bf1[0], a0[mt], z0, 0, 0, 0);
            z1 = __builtin_amdgcn_mfma_f32_16x16x32_bf16(Bf1[1], a0[mt], z1, 0, 0, 0);
            // pack |z| as permuted B-operand fragment (k = lq*8+i -> ch pi(k))
            union { u32 u[4]; bf16x8 h; } zf;
            zf.u[0] = pk2(fabsf(z0[0]), fabsf(z0[1]));
            zf.u[1] = pk2(fabsf(z0[2]), fabsf(z0[3]));
            zf.u[2] = pk2(fabsf(z1[0]), fabsf(z1[1]));
            zf.u[3] = pk2(fabsf(z1[2]), fabsf(z1[3]));
            // round 2: logits m[n][px] = M2p*|z| + B2*a0
            f32x4 c0 = {0.f, 0.f, 0.f, 0.f}, c1 = {0.f, 0.f, 0.f, 0.f};
            c0 = __builtin_amdgcn_mfma_f32_16x16x32_bf16(M2p[0], zf.h,   c0, 0, 0, 0);
            c0 = __builtin_amdgcn_mfma_f32_16x16x32_bf16(Bf2[0], a0[mt], c0, 0, 0, 0);
            c1 = __builtin_amdgcn_mfma_f32_16x16x32_bf16(M2p[1], zf.h,   c1, 0, 0, 0);
            c1 = __builtin_amdgcn_mfma_f32_16x16x32_bf16(Bf2[1], a0[mt], c1, 0, 0, 0);
            // scatter: lane(l16,lq) holds n = lq*4..+3 (c0) / 16+lq*4..+3 (c1)
            // for pixel mt*16+l16.  c0 -> bytes 64..127, c1 -> bytes 0..63.
            *(f32x4*)(ab + ((64 + lq * 16) ^ asx)) = c0;
            *(f32x4*)(ab + ((lq * 16) ^ asx))      = c1;
        }

        lds_fence();   // scatters -> readback

        // ---- readback 27 logits: n0..15 @ bytes 64..127, n16..26 @ 0..47 ----
        f32x4 mv[7];
#pragma unroll
        for (int q = 0; q < 4; ++q)
            mv[q] = *(const f32x4*)(myrow + ((64 + q * 16) ^ sx));
#pragma unroll
        for (int q = 0; q < 3; ++q)
            mv[4 + q] = *(const f32x4*)(myrow + ((q * 16) ^ sx));

        const int p    = tb * 256 + tid;
        const int wcol = p & (WW - 1);
        const int t    = p >> 9;
        const int hrow = t & (HH - 1);
        const int bidx = t >> 9;
        const size_t ob = ((size_t)(bidx * HH + hrow) * (WW * 3)) + (size_t)wcol * 3;
#pragma unroll
        for (int v = 0; v < 3; ++v) {
            float ssum = 0.0f, acc = 0.0f;
#pragma unroll
            for (int k = 0; k < 9; ++k) {
                const int j = k * 3 + v;
                const float lg = (j < 16) ? mv[j >> 2][j & 3]
                                          : mv[4 + ((j - 16) >> 2)][(j - 16) & 3];
                const float e = __builtin_amdgcn_exp2f(lg);
                ssum += e;
                acc = fmaf(xv[k], e, acc);
            }
            out[ob + v] = acc * __builtin_amdgcn_rcpf(ssum);
        }

        lds_fence();   // readback -> next iteration's init writes

        tb = tn;
#pragma unroll
        for (int k = 0; k < 9; ++k) xv[k] = xn[k];
    }
}

extern "C" void kernel_launch(void* const* d_in, const int* in_sizes, int n_in,
                              void* d_out, int out_size, void* d_ws, size_t ws_size,
                              hipStream_t stream) {
    // setup_inputs order: x, target_h, target_w, w1, b1, alpha, w2, b2
    const float* x     = (const float*)d_in[0];
    const float* w1    = (const float*)d_in[3];
    const float* b1    = (const float*)d_in[4];
    const float* alpha = (const float*)d_in[5];
    const float* w2    = (const float*)d_in[6];
    const float* b2    = (const float*)d_in[7];
    float* out = (float*)d_out;
    __hip_bfloat16* ws = (__hip_bfloat16*)d_ws;   // 3072 bf16 = 6 KB

    hipLaunchKernelGGL(prep_B, dim3(12), dim3(256), 0, stream, w1, b1, alpha, w2, b2, ws);
    hipLaunchKernelGGL(convex_upsample_mfma8, dim3(NBLK), dim3(256), 0, stream,
                       x, ws, out);
}

// Round 13
// 61.103 us; speedup vs baseline: 1.3076x; 1.3076x over previous
//
#include <hip/hip_runtime.h>
#include <hip/hip_bf16.h>

// ConvexWidthUpsampler R13: R11 structure + 112B self-swizzling rows ->
// 28736 B/block -> TRUE 5 blocks/CU (20KB slack). No XOR swizzle needed:
// row stride 112 = 7x16B rotates the 16B-block index by 7 mod 8 per row.
// z stays in registers (permuted-M2 trick, R11-proven):
//   Round 1: z[n,px] = mfma(B1, a0); packed |z| is a legal B-operand under
//   channel perm pi(k) = (k&4?16:0)+(k>>3)*4+(k&3) (M2p pre-permuted).
//   Round 2: m = mfma(M2p, zfrag) + mfma(B2, a0) -- no z LDS roundtrip.
// Row layout (112B): bytes 0..31 = k0..15 input (xv,1,0); after a0 reads,
// c1 (n16..27) overwrites bytes 0..47 (lq<3 only), c0 (n0..15) -> 48..111.
// a0 k16..31 zeros come from a 16B broadcast-zero block at wave offset 7168.
// Persistent grid NBLK=1280 (5 blocks/CU x 256 CU), 13/12 tiles per block,
// x prefetched 1 tile ahead. B=16,C=1,H=512,W=512,up=(1,3). Out f32.

#define BB 16
#define HH 512
#define WW 512
#define HID 32
#define NM 27
#define LOG2E 1.44269504088896340736f
#define NT 16384
#define NBLK 1280
#define ROWB 112
#define ZOFF (64 * ROWB)   // 7168: per-wave broadcast-zero block

typedef short bf16x8 __attribute__((ext_vector_type(8)));
typedef float f32x4  __attribute__((ext_vector_type(4)));
typedef unsigned int u32;
typedef u32 u32x4 __attribute__((ext_vector_type(4)));

__device__ __forceinline__ u32 pk2(float a, float b) {
    union { __hip_bfloat162 h2; u32 u; } cv;
    cv.h2 = __float22bfloat162_rn(make_float2(a, b));
    return cv.u;
}

// Compiler memory fence (free at runtime): blocks CSE/TBAA reordering of LDS
// ops across stages; a wave's DS instructions execute in issue order in HW.
__device__ __forceinline__ void lds_fence() {
    asm volatile("" ::: "memory");
    __builtin_amdgcn_sched_barrier(0);
}

// Clamped-address 3x3 load: addresses always in-bounds, zeros via cndmask.
__device__ __forceinline__ void load_xv(const float* __restrict__ x, int tile,
                                        int tid, float xv[9]) {
    const int p    = tile * 256 + tid;
    const int wcol = p & (WW - 1);
    const int t    = p >> 9;
    const int hrow = t & (HH - 1);
    const int bidx = t >> 9;
    const float* xb = x + (size_t)bidx * (HH * WW);
    int hy[3], wx[3];
    bool hok[3], wok[3];
#pragma unroll
    for (int i = 0; i < 3; ++i) {
        const int h = hrow + i - 1;
        hok[i] = (unsigned)h < (unsigned)HH;
        hy[i]  = h < 0 ? 0 : (h > HH - 1 ? HH - 1 : h);
        const int w = wcol + i - 1;
        wok[i] = (unsigned)w < (unsigned)WW;
        wx[i]  = w < 0 ? 0 : (w > WW - 1 ? WW - 1 : w);
    }
#pragma unroll
    for (int ki = 0; ki < 3; ++ki)
#pragma unroll
        for (int kj = 0; kj < 3; ++kj) {
            const float v = xb[hy[ki] * WW + wx[kj]];
            xv[ki * 3 + kj] = (hok[ki] && wok[kj]) ? v : 0.0f;
        }
}

// ws bf16 layout (hi-only, 3072 elems = 6 KB):
//   [0   ..1023] B2_32 [32 n][32 k]: k<9 M1[n][k], k==9 bias'[n], else 0 (xlog2e)
//   [1024..2047] M2p   [32 n][32 k]: M2[n][pi(k)] (xlog2e), n>=27 -> 0
//   [2048..3071] B1    [32 n][32 k]: k<9 w1[n][k], k==9 b1[n], else 0
__global__ void prep_B(const float* __restrict__ w1, const float* __restrict__ b1,
                       const float* __restrict__ alpha, const float* __restrict__ w2,
                       const float* __restrict__ b2, __hip_bfloat16* __restrict__ ws) {
    const int i = blockIdx.x * 256 + threadIdx.x;
    if (i >= 3072) return;
    const int sec = i >> 10;
    const int r   = i & 1023;
    const int n   = r >> 5, k = r & 31;
    float v = 0.0f;
    if (sec == 0) {
        if (n < NM) {
            if (k < 9) {
                for (int c = 0; c < HID; ++c)
                    v += w2[n * HID + c] * (0.5f * (1.0f + alpha[c])) * w1[c * 9 + k];
            } else if (k == 9) {
                v = b2[n];
                for (int c = 0; c < HID; ++c)
                    v += w2[n * HID + c] * (0.5f * (1.0f + alpha[c])) * b1[c];
            }
        }
        v *= LOG2E;
    } else if (sec == 1) {
        if (n < NM) {
            const int c = ((k & 4) ? 16 : 0) + (k >> 3) * 4 + (k & 3);  // pi(k)
            v = w2[n * HID + c] * (0.5f * (1.0f - alpha[c])) * LOG2E;
        }
    } else {
        v = (k < 9) ? w1[n * 9 + k] : (k == 9 ? b1[n] : 0.0f);
    }
    ws[i] = __float2bfloat16(v);
}

__global__ __launch_bounds__(256, 5) void convex_upsample_mfma9(
    const float* __restrict__ x,            // [16,1,512,512]
    const __hip_bfloat16* __restrict__ ws,  // prep output
    float* __restrict__ out)                // [16,1,512,1536]
{
    __shared__ char lds_raw[4][ZOFF + 16];  // 4 x 7184 = 28736 B -> 5 blocks/CU

    const int tid  = threadIdx.x;
    const int wv   = tid >> 6;
    const int lane = tid & 63;
    const int l16  = lane & 15;
    const int lq   = lane >> 4;
    char* wbase = lds_raw[wv];

    // persistent weight fragments (hi only): lane row n = nt*16+l16, k = lq*8+i
    bf16x8 Bf2[2], M2p[2], Bf1[2];
#pragma unroll
    for (int nt = 0; nt < 2; ++nt) {
        const int ro = (nt * 16 + l16) * 32 + lq * 8;
        Bf2[nt] = *(const bf16x8*)(ws + ro);
        M2p[nt] = *(const bf16x8*)(ws + 1024 + ro);
        Bf1[nt] = *(const bf16x8*)(ws + 2048 + ro);
    }

    // broadcast-zero block (idempotent per-wave write; read by lq>=2 a0 loads)
    *(u32x4*)(wbase + ZOFF) = (u32x4){0u, 0u, 0u, 0u};

    int tb = blockIdx.x;
    float xv[9];
    load_xv(x, tb, tid, xv);

    while (tb < NT) {
        const int tn  = tb + NBLK;
        const int tpf = (tn < NT) ? tn : 0;
        float xn[9];
        load_xv(x, tpf, tid, xn);   // prefetch next tile during this compute

        // ---- init my row bytes 0..31: k0..8=xv, k9=1, k10..15=0 ----
        char* myrow = wbase + lane * ROWB;
        *(u32x4*)(myrow)      = (u32x4){pk2(xv[0], xv[1]), pk2(xv[2], xv[3]),
                                        pk2(xv[4], xv[5]), pk2(xv[6], xv[7])};
        *(u32x4*)(myrow + 16) = (u32x4){pk2(xv[8], 1.0f), 0u, 0u, 0u};

        lds_fence();   // init writes -> cross-lane a0 reads

        // ---- hoisted a0 reads; lq>=2 lanes read the broadcast-zero block ----
        bf16x8 a0[4];
#pragma unroll
        for (int mt = 0; mt < 4; ++mt) {
            const char* ab = wbase + (mt * 16 + l16) * ROWB;
            const char* aptr = (lq < 2) ? (ab + lq * 16) : (wbase + ZOFF);
            a0[mt] = *(const bf16x8*)aptr;
        }

        lds_fence();   // a0 reads -> scatters below (TBAA/reorder guard)

        // ---- per mt: z in-register -> logits -> scatter ----
#pragma unroll
        for (int mt = 0; mt < 4; ++mt) {
            char* ab = wbase + (mt * 16 + l16) * ROWB;
            // round 1: z[ch][px]; lane(l16,lq) gets ch = {lq*4+r, 16+lq*4+r}, px = l16
            f32x4 z0 = {0.f, 0.f, 0.f, 0.f}, z1 = {0.f, 0.f, 0.f, 0.f};
            z0 = __builtin_amdgcn_mfma_f32_16x16x32_bf16(Bf1[0], a0[mt], z0, 0, 0, 0);
            z1 = __builtin_amdgcn_mfma_f32_16x16x32_bf16(Bf1[1], a0[mt], z1, 0, 0, 0);
            // pack |z| as permuted B-operand fragment (k = lq*8+i -> ch pi(k))
            union { u32 u[4]; bf16x8 h; } zf;
            zf.u[0] = pk2(fabsf(z0[0]), fabsf(z0[1]));
            zf.u[1] = pk2(fabsf(z0[2]), fabsf(z0[3]));
            zf.u[2] = pk2(fabsf(z1[0]), fabsf(z1[1]));
            zf.u[3] = pk2(fabsf(z1[2]), fabsf(z1[3]));
            // round 2: logits m[n][px] = M2p*|z| + B2*a0
            f32x4 c0 = {0.f, 0.f, 0.f, 0.f}, c1 = {0.f, 0.f, 0.f, 0.f};
            c0 = __builtin_amdgcn_mfma_f32_16x16x32_bf16(M2p[0], zf.h,   c0, 0, 0, 0);
            c0 = __builtin_amdgcn_mfma_f32_16x16x32_bf16(Bf2[0], a0[mt], c0, 0, 0, 0);
            c1 = __builtin_amdgcn_mfma_f32_16x16x32_bf16(M2p[1], zf.h,   c1, 0, 0, 0);
            c1 = __builtin_amdgcn_mfma_f32_16x16x32_bf16(Bf2[1], a0[mt], c1, 0, 0, 0);
            // scatter for pixel mt*16+l16: lane(l16,lq) holds
            //   c0: n = lq*4..+3      -> bytes 48 + lq*16 (48..111)
            //   c1: n = 16+lq*4..+3   -> bytes lq*16 (0..47), lq==3 (n>=28) dropped
            *(f32x4*)(ab + 48 + lq * 16) = c0;
            if (lq < 3) *(f32x4*)(ab + lq * 16) = c1;
        }

        lds_fence();   // scatters -> readback

        // ---- readback 27 logits: n0..15 @ bytes 48..111, n16..26 @ 0..43 ----
        f32x4 mv[7];
#pragma unroll
        for (int q = 0; q < 4; ++q)
            mv[q] = *(const f32x4*)(myrow + 48 + q * 16);
#pragma unroll
        for (int q = 0; q < 3; ++q)
            mv[4 + q] = *(const f32x4*)(myrow + q * 16);

        const int p    = tb * 256 + tid;
        const int wcol = p & (WW - 1);
        const int t    = p >> 9;
        const int hrow = t & (HH - 1);
        const int bidx = t >> 9;
        const size_t ob = ((size_t)(bidx * HH + hrow) * (WW * 3)) + (size_t)wcol * 3;
#pragma unroll
        for (int v = 0; v < 3; ++v) {
            float ssum = 0.0f, acc = 0.0f;
#pragma unroll
            for (int k = 0; k < 9; ++k) {
                const int j = k * 3 + v;
                const float lg = (j < 16) ? mv[j >> 2][j & 3]
                                          : mv[4 + ((j - 16) >> 2)][(j - 16) & 3];
                const float e = __builtin_amdgcn_exp2f(lg);
                ssum += e;
                acc = fmaf(xv[k], e, acc);
            }
            out[ob + v] = acc * __builtin_amdgcn_rcpf(ssum);
        }

        lds_fence();   // readback -> next iteration's init writes

        tb = tn;
#pragma unroll
        for (int k = 0; k < 9; ++k) xv[k] = xn[k];
    }
}

extern "C" void kernel_launch(void* const* d_in, const int* in_sizes, int n_in,
                              void* d_out, int out_size, void* d_ws, size_t ws_size,
                              hipStream_t stream) {
    // setup_inputs order: x, target_h, target_w, w1, b1, alpha, w2, b2
    const float* x     = (const float*)d_in[0];
    const float* w1    = (const float*)d_in[3];
    const float* b1    = (const float*)d_in[4];
    const float* alpha = (const float*)d_in[5];
    const float* w2    = (const float*)d_in[6];
    const float* b2    = (const float*)d_in[7];
    float* out = (float*)d_out;
    __hip_bfloat16* ws = (__hip_bfloat16*)d_ws;   // 3072 bf16 = 6 KB

    hipLaunchKernelGGL(prep_B, dim3(12), dim3(256), 0, stream, w1, b1, alpha, w2, b2, ws);
    hipLaunchKernelGGL(convex_upsample_mfma9, dim3(NBLK), dim3(256), 0, stream,
                       x, ws, out);
}